// Round 8
// baseline (814.107 us; speedup 1.0000x reference)
//
#include <hip/hip_runtime.h>
#include <cmath>

namespace {

constexpr int B = 64, N = 5000, DIN = 64, DMID = 128, DOUT = 32, E = 80000;
constexpr int NT = (N + 63) / 64;  // 79 tiles

typedef unsigned short u16;
typedef __attribute__((ext_vector_type(8))) short short8;
typedef __attribute__((ext_vector_type(4))) float floatx4;

#define MFMA16(a, b, c) __builtin_amdgcn_mfma_f32_16x16x32_bf16((a), (b), (c), 0, 0, 0)

__device__ __forceinline__ u16 f2bf(float f) {
  union { float f; unsigned u; } v; v.f = f;
  unsigned r = v.u + 0x7FFFu + ((v.u >> 16) & 1u);  // RNE
  return (u16)(r >> 16);
}
__device__ __forceinline__ float bf2f(u16 s) {
  union { unsigned u; float f; } v; v.u = ((unsigned)s) << 16;
  return v.f;
}
__device__ __forceinline__ float sigmoid_fast(float x) {
  return __builtin_amdgcn_rcpf(1.f + __expf(-x));   // saturates cleanly at +-inf
}
__device__ __forceinline__ float tanh_fast(float x) {
  return fmaf(2.f, __builtin_amdgcn_rcpf(1.f + __expf(-2.f * x)), -1.f);
}

// ---------------- graph build ----------------

__global__ void count_kernel(const int* __restrict__ ei, int* counts) {
  int e = blockIdx.x * 256 + threadIdx.x;
  if (e < E) atomicAdd(&counts[ei[E + e]], 1);
}

// scan also re-zeroes counts (fill_kernel reuses counts as its cursor array)
__global__ void scan_kernel(int* counts, int* rowptr, float* dis) {
  __shared__ int sdata[1024];
  const int tid = threadIdx.x;
  constexpr int CH = (N + 1023) / 1024;  // 5
  int local[CH], cnt[CH];
  int s = 0;
  for (int i = 0; i < CH; i++) {
    int idx = tid * CH + i;
    int c = (idx < N) ? counts[idx] : 0;
    cnt[i] = c;
    local[i] = s;
    s += c;
  }
  sdata[tid] = s;
  __syncthreads();
  for (int off = 1; off < 1024; off <<= 1) {
    int v = (tid >= off) ? sdata[tid - off] : 0;
    __syncthreads();
    sdata[tid] += v;
    __syncthreads();
  }
  int prev = (tid > 0) ? sdata[tid - 1] : 0;
  for (int i = 0; i < CH; i++) {
    int idx = tid * CH + i;
    if (idx < N) {
      rowptr[idx] = prev + local[i];
      dis[idx] = rsqrtf((float)(cnt[i] + 1));  // + self loop
      counts[idx] = 0;                         // reset cursor for fill
    }
  }
  if (tid == 1023) rowptr[N] = sdata[1023];
}

__global__ void fill_kernel(const int* __restrict__ ei, const int* __restrict__ rowptr,
                            const float* __restrict__ dis, int* counts,
                            int* csr_src, float* csr_w) {
  int e = blockIdx.x * 256 + threadIdx.x;
  if (e >= E) return;
  int r = ei[e], c = ei[E + e];
  int pos = rowptr[c] + atomicAdd(&counts[c], 1);
  csr_src[pos] = r;
  csr_w[pos] = dis[r] * dis[c];
}

// ---------------- weight packing ----------------
// Algebraic fold: gate_pre = xs @ (Wg @ Wl_low) + H @ Wl_high + (bg @ Wl_low + bl)
// B-frag convention (16x16x32): lane l holds B[k=(l>>4)*8+jj][n=l&15], jj linear.
// wcB: combined conv weights [64x128] per gate, chunk c = g*16 + kt*8 + nt (kt<2)
// whB: Wl high-half [128x128] per gate, chunk c = g*32 + kt*8 + nt (kt<4)
// bcAll[g*128+n] = bg_g @ Wl_low + bl_g

__global__ void pack_kernel(const float* Wgz, const float* Wgr, const float* Wgh,
                            const float* Wlz, const float* Wlr, const float* Wlh,
                            const float* bgz, const float* bgr, const float* bgh,
                            const float* blz, const float* blr, const float* blh,
                            u16* wcB, u16* whB, float* bcAll) {
  int t = blockIdx.x * 256 + threadIdx.x;
  const float* Wg[3] = {Wgz, Wgr, Wgh};
  const float* Wl[3] = {Wlz, Wlr, Wlh};
  const float* bg[3] = {bgz, bgr, bgh};
  const float* bl[3] = {blz, blr, blh};
  if (t < 48 * 64) {
    // combined conv weights: Wc_g[k][n] = sum_j Wg_g[k][j] * Wl_g[j][n]
    int chunk = t >> 6, lane = t & 63;
    int q = lane >> 4, lm = lane & 15;
    int g = chunk >> 4, rem = chunk & 15, kt = rem >> 3, nt = rem & 7;
    int n = nt * 16 + lm;
#pragma unroll
    for (int jj = 0; jj < 8; jj++) {
      int k = kt * 32 + q * 8 + jj;   // < 64
      float acc = 0.f;
      for (int j = 0; j < DMID; j++)
        acc = fmaf(Wg[g][k * DMID + j], Wl[g][j * DMID + n], acc);
      wcB[(size_t)(chunk * 64 + lane) * 8 + jj] = f2bf(acc);
    }
  } else if (t < 48 * 64 + 96 * 64) {
    int t2 = t - 48 * 64;
    int chunk = t2 >> 6, lane = t2 & 63;
    int q = lane >> 4, lm = lane & 15;
    int g = chunk >> 5, rem = chunk & 31, kt = rem >> 3, nt = rem & 7;
    int n = nt * 16 + lm;
#pragma unroll
    for (int jj = 0; jj < 8; jj++) {
      int k = kt * 32 + q * 8 + jj;   // < 128
      whB[(size_t)t2 * 8 + jj] = f2bf(Wl[g][(DMID + k) * DMID + n]);
    }
  } else {
    int t3 = t - 48 * 64 - 96 * 64;
    if (t3 < 384) {
      int g = t3 >> 7, n = t3 & 127;
      float acc = bl[g][n];
      for (int j = 0; j < DMID; j++)
        acc = fmaf(bg[g][j], Wl[g][j * DMID + n], acc);
      bcAll[t3] = acc;
    }
  }
}

// ---------------- aggregation v3: one block per dst node, all 64 batches ----------------
// 256 threads = 64 batches x 4 d-quarters (16 floats each). The CSR edge list
// is decoded ONCE per node (vs 64x before); every thread processes the same
// edge -> zero divergence; per edge the block reads x[b][src][:] for all b
// via fully-coalesced dwordx4. ~5x fewer dynamic instructions than per-(b,n).

__global__ __launch_bounds__(256) void agg_kernel(
    const float* __restrict__ x, const int* __restrict__ rowptr,
    const int* __restrict__ csr_src, const float* __restrict__ csr_w,
    const float* __restrict__ dis, u16* __restrict__ xs) {
  const int n = blockIdx.x;              // dst node
  const int tb = threadIdx.x >> 2;       // batch 0..63
  const int dq = threadIdx.x & 3;        // d-quarter 0..3
  const float* xbase = x + (size_t)tb * N * DIN + dq * 16;

  const float d = dis[n];
  const float sw = d * d;
  float4 acc[4];
  {
    const float4* sp = (const float4*)(xbase + (size_t)n * DIN);
#pragma unroll
    for (int i = 0; i < 4; i++) {
      float4 v = sp[i];
      acc[i].x = v.x * sw; acc[i].y = v.y * sw;
      acc[i].z = v.z * sw; acc[i].w = v.w * sw;
    }
  }
  const int s1 = rowptr[n + 1];
  int p = rowptr[n];
  for (; p + 2 <= s1; p += 2) {
    int i0 = csr_src[p], i1 = csr_src[p + 1];
    float w0 = csr_w[p], w1 = csr_w[p + 1];
    const float4* s0p = (const float4*)(xbase + (size_t)i0 * DIN);
    const float4* s1p = (const float4*)(xbase + (size_t)i1 * DIN);
    float4 a0[4], a1[4];
#pragma unroll
    for (int i = 0; i < 4; i++) a0[i] = s0p[i];
#pragma unroll
    for (int i = 0; i < 4; i++) a1[i] = s1p[i];
#pragma unroll
    for (int i = 0; i < 4; i++) {
      acc[i].x = fmaf(a0[i].x, w0, acc[i].x); acc[i].y = fmaf(a0[i].y, w0, acc[i].y);
      acc[i].z = fmaf(a0[i].z, w0, acc[i].z); acc[i].w = fmaf(a0[i].w, w0, acc[i].w);
    }
#pragma unroll
    for (int i = 0; i < 4; i++) {
      acc[i].x = fmaf(a1[i].x, w1, acc[i].x); acc[i].y = fmaf(a1[i].y, w1, acc[i].y);
      acc[i].z = fmaf(a1[i].z, w1, acc[i].z); acc[i].w = fmaf(a1[i].w, w1, acc[i].w);
    }
  }
  if (p < s1) {
    int i0 = csr_src[p];
    float w0 = csr_w[p];
    const float4* s0p = (const float4*)(xbase + (size_t)i0 * DIN);
#pragma unroll
    for (int i = 0; i < 4; i++) {
      float4 v = s0p[i];
      acc[i].x = fmaf(v.x, w0, acc[i].x); acc[i].y = fmaf(v.y, w0, acc[i].y);
      acc[i].z = fmaf(v.z, w0, acc[i].z); acc[i].w = fmaf(v.w, w0, acc[i].w);
    }
  }
  uint4 o0, o1;
  o0.x = (unsigned)f2bf(acc[0].x) | ((unsigned)f2bf(acc[0].y) << 16);
  o0.y = (unsigned)f2bf(acc[0].z) | ((unsigned)f2bf(acc[0].w) << 16);
  o0.z = (unsigned)f2bf(acc[1].x) | ((unsigned)f2bf(acc[1].y) << 16);
  o0.w = (unsigned)f2bf(acc[1].z) | ((unsigned)f2bf(acc[1].w) << 16);
  o1.x = (unsigned)f2bf(acc[2].x) | ((unsigned)f2bf(acc[2].y) << 16);
  o1.y = (unsigned)f2bf(acc[2].z) | ((unsigned)f2bf(acc[2].w) << 16);
  o1.z = (unsigned)f2bf(acc[3].x) | ((unsigned)f2bf(acc[3].y) << 16);
  o1.w = (unsigned)f2bf(acc[3].z) | ((unsigned)f2bf(acc[3].w) << 16);
  u16* out = xs + ((size_t)tb * N + n) * DIN + dq * 16;
  *(uint4*)out = o0;
  *(uint4*)(out + 8) = o1;
}

// ---------------- fused MFMA kernel (barrier-free, wave-independent) ----------------
// 256 threads = 4 waves; wave w owns rows [w*16, w*16+16) and touches only its
// own 16 LDS rows. No __syncthreads.
// (256,3): 170 unified regs/wave -> no scratch spill (R3/R5/R6 showed the
// +130..220MB WRITE excess tracks the reg cap; 128-reg cap still spilled).
//   ph1: r-gate + H*R per nt (H stashed as raw bf16 bits, uint2 x 8)
//   ph2: z-gate pre-activations (zpre, 32 regs); ah dies here
//   ph3: h-gate (ax + ahr only) + blend + store
// LDS: 64*136*2 = 17408 B.

constexpr int SH = 136;  // stride for 128-wide bf16 tiles (16B-aligned rows)

__global__ __launch_bounds__(256, 3) void fused_mfma(
    const u16* __restrict__ xs, const float* __restrict__ H,
    const u16* __restrict__ wcB, const u16* __restrict__ whB,
    const float* __restrict__ bcAll,
    float* __restrict__ hnew, float* __restrict__ partials) {
  __shared__ u16 H_s[64 * SH];  // H tile bf16; each wave owns 16 rows

  const int tid = threadIdx.x;
  const int b = blockIdx.y;
  const int n0 = blockIdx.x * 64;
  const int lane = tid & 63, w = tid >> 6;
  const int q = lane >> 4, lm = lane & 15;
  const int w16 = w * 16;

  // ---- stage this wave's 16 H rows, fp32 -> bf16 ----
#pragma unroll
  for (int j = 0; j < 8; j++) {
    int idx = j * 64 + lane;            // 0..511
    int rl = idx >> 5, seg = idx & 31;  // row-local 0..15, col-seg 0..31
    int row = w16 + rl;
    float4 v = make_float4(0.f, 0.f, 0.f, 0.f);
    if (n0 + row < N) v = *(const float4*)(H + ((size_t)b * N + n0 + row) * DMID + seg * 4);
    uint2 p;
    p.x = (unsigned)f2bf(v.x) | ((unsigned)f2bf(v.y) << 16);
    p.y = (unsigned)f2bf(v.z) | ((unsigned)f2bf(v.w) << 16);
    *(uint2*)&H_s[row * SH + seg * 4] = p;
  }

  // ---- xs A-frags direct from global ----
  const int an = n0 + w16 + lm;  // this lane's A-row
  short8 ax[2];
  if (an < N) {
    const u16* xrow = xs + ((size_t)b * N + an) * DIN;
    ax[0] = *(const short8*)(xrow + q * 8);
    ax[1] = *(const short8*)(xrow + 32 + q * 8);
  } else {
    ax[0] = short8{0, 0, 0, 0, 0, 0, 0, 0};
    ax[1] = short8{0, 0, 0, 0, 0, 0, 0, 0};
  }

  // ---- H A-frags (own rows; ds-ordering via lgkmcnt, no barrier needed) ----
  short8 ah[4];
#pragma unroll
  for (int kt = 0; kt < 4; kt++)
    ah[kt] = *(const short8*)&H_s[(w16 + lm) * SH + kt * 32 + q * 8];

  // ---- phase 1: r gate fused with H*R in-place update (own rows) ----
  // hstash: raw bf16 bits of original H (C layout), 2 regs per nt.
  uint2 hstash[8];
#pragma unroll
  for (int nt = 0; nt < 8; nt++) {
    floatx4 a = {0.f, 0.f, 0.f, 0.f};
#pragma unroll
    for (int kt = 0; kt < 2; kt++)
      a = MFMA16(ax[kt], *(const short8*)(wcB + (size_t)((16 + kt * 8 + nt) * 64 + lane) * 8), a);
#pragma unroll
    for (int kt = 0; kt < 4; kt++)
      a = MFMA16(ah[kt], *(const short8*)(whB + (size_t)((32 + kt * 8 + nt) * 64 + lane) * 8), a);
    float bias = bcAll[128 + nt * 16 + lm];
    unsigned hx = 0u, hy = 0u;
#pragma unroll
    for (int r = 0; r < 4; r++) {
      int row = w16 + q * 4 + r, col = nt * 16 + lm;
      u16 hb = H_s[row * SH + col];
      float h = bf2f(hb);
      float rg = sigmoid_fast(a[r] + bias);
      H_s[row * SH + col] = f2bf(h * rg);
      if (r < 2) hx |= ((unsigned)hb) << (16 * r);
      else       hy |= ((unsigned)hb) << (16 * (r - 2));
    }
    hstash[nt] = make_uint2(hx, hy);
  }

  // ---- phase 2: z gate pre-activations (last use of ah) ----
  floatx4 zpre[8];
#pragma unroll
  for (int nt = 0; nt < 8; nt++) {
    floatx4 a = {0.f, 0.f, 0.f, 0.f};
#pragma unroll
    for (int kt = 0; kt < 2; kt++)
      a = MFMA16(ax[kt], *(const short8*)(wcB + (size_t)((0 + kt * 8 + nt) * 64 + lane) * 8), a);
#pragma unroll
    for (int kt = 0; kt < 4; kt++)
      a = MFMA16(ah[kt], *(const short8*)(whB + (size_t)((0 + kt * 8 + nt) * 64 + lane) * 8), a);
    zpre[nt] = a;
  }

  // ---- HR A-frags (own rows, written by this wave in phase 1) ----
  short8 ahr[4];
#pragma unroll
  for (int kt = 0; kt < 4; kt++)
    ahr[kt] = *(const short8*)&H_s[(w16 + lm) * SH + kt * 32 + q * 8];

  // ---- phase 3: h gate, blend, store, per-wave partial sums ----
#pragma unroll
  for (int nt = 0; nt < 8; nt++) {
    floatx4 ha = {0.f, 0.f, 0.f, 0.f};
#pragma unroll
    for (int kt = 0; kt < 2; kt++)
      ha = MFMA16(ax[kt], *(const short8*)(wcB + (size_t)((32 + kt * 8 + nt) * 64 + lane) * 8), ha);
#pragma unroll
    for (int kt = 0; kt < 4; kt++)
      ha = MFMA16(ahr[kt], *(const short8*)(whB + (size_t)((64 + kt * 8 + nt) * 64 + lane) * 8), ha);
    float zb = bcAll[nt * 16 + lm], hb_ = bcAll[256 + nt * 16 + lm];
    float colsum = 0.f;
#pragma unroll
    for (int r = 0; r < 4; r++) {
      int row = w16 + q * 4 + r;
      bool valid = (n0 + row) < N;
      unsigned word = (r < 2) ? hstash[nt].x : hstash[nt].y;
      float h = bf2f((u16)(word >> (16 * (r & 1))));
      float z = sigmoid_fast(zpre[nt][r] + zb);
      float ht = tanh_fast(ha[r] + hb_);
      float hn = fmaf(z, h - ht, ht);  // z*H + (1-z)*ht
      if (valid) {
        hnew[((size_t)b * N + n0 + row) * DMID + nt * 16 + lm] = hn;
        colsum += hn;
      }
    }
    colsum += __shfl_xor(colsum, 16);
    colsum += __shfl_xor(colsum, 32);
    if (lane < 16)
      partials[(((size_t)b * NT + blockIdx.x) * 4 + w) * DMID + nt * 16 + lane] = colsum;
  }
}

// ---------------- output head: reduce per-wave partials, relu, Wout ----------------

__global__ void out_kernel(const float* __restrict__ partials, const float* __restrict__ Wout,
                           const float* __restrict__ bout, float* __restrict__ y) {
  const int b = blockIdx.x;
  const int c = threadIdx.x;  // 128
  __shared__ float m[DMID];
  float acc = 0.f;
  for (int t = 0; t < NT * 4; t++)
    acc += partials[((size_t)b * NT * 4 + t) * DMID + c];
  m[c] = fmaxf(acc * (1.f / (float)N), 0.f);
  __syncthreads();
  if (c < DOUT) {
    float a2 = bout[c];
    for (int jj = 0; jj < DMID; jj++)
      a2 = fmaf(m[jj], Wout[jj * DOUT + c], a2);
    y[b * DOUT + c] = a2;
  }
}

}  // namespace

extern "C" void kernel_launch(void* const* d_in, const int* in_sizes, int n_in,
                              void* d_out, int out_size, void* d_ws, size_t ws_size,
                              hipStream_t stream) {
  const float* x = (const float*)d_in[0];
  const int* ei = (const int*)d_in[1];
  const float* H = (const float*)d_in[2];
  const float* Wgz = (const float*)d_in[3];
  const float* bgz = (const float*)d_in[4];
  const float* Wgr = (const float*)d_in[5];
  const float* bgr = (const float*)d_in[6];
  const float* Wgh = (const float*)d_in[7];
  const float* bgh = (const float*)d_in[8];
  const float* Wlz = (const float*)d_in[9];
  const float* blz = (const float*)d_in[10];
  const float* Wlr = (const float*)d_in[11];
  const float* blr = (const float*)d_in[12];
  const float* Wlh = (const float*)d_in[13];
  const float* blh = (const float*)d_in[14];
  const float* Wout = (const float*)d_in[15];
  const float* bout = (const float*)d_in[16];

  float* y = (float*)d_out;                        // [B, DOUT]
  float* hnew = (float*)d_out + (size_t)B * DOUT;  // [B, N, DMID]

  char* p = (char*)d_ws;
  auto carve = [&](size_t bytes) {
    char* q = p;
    p += (bytes + 255) & ~size_t(255);
    return q;
  };
  int* counts = (int*)carve((size_t)N * 4);
  int* rowptr = (int*)carve((size_t)(N + 1) * 4);
  int* csr_src = (int*)carve((size_t)E * 4);
  float* csr_w = (float*)carve((size_t)E * 4);
  float* dis = (float*)carve((size_t)N * 4);
  u16* wcB = (u16*)carve((size_t)48 * 64 * 8 * 2);
  u16* whB = (u16*)carve((size_t)96 * 64 * 8 * 2);
  float* bcAll = (float*)carve((size_t)384 * 4);
  float* partials = (float*)carve((size_t)B * NT * 4 * DMID * 4);  // 10.4 MB
  u16* xs = (u16*)carve((size_t)B * N * DIN * 2);  // ~41 MB

  hipMemsetAsync(counts, 0, (size_t)N * 4, stream);
  pack_kernel<<<38, 256, 0, stream>>>(Wgz, Wgr, Wgh, Wlz, Wlr, Wlh,
                                      bgz, bgr, bgh, blz, blr, blh,
                                      wcB, whB, bcAll);
  count_kernel<<<(E + 255) / 256, 256, 0, stream>>>(ei, counts);
  scan_kernel<<<1, 1024, 0, stream>>>(counts, rowptr, dis);
  fill_kernel<<<(E + 255) / 256, 256, 0, stream>>>(ei, rowptr, dis, counts, csr_src, csr_w);
  agg_kernel<<<N, 256, 0, stream>>>(x, rowptr, csr_src, csr_w, dis, xs);
  fused_mfma<<<dim3(NT, B), 256, 0, stream>>>(xs, H, wcB, whB, bcAll, hnew, partials);
  out_kernel<<<B, DMID, 0, stream>>>(partials, Wout, bout, y);
}

// Round 9
// 702.561 us; speedup vs baseline: 1.1588x; 1.1588x over previous
//
#include <hip/hip_runtime.h>
#include <cmath>

namespace {

constexpr int B = 64, N = 5000, DIN = 64, DMID = 128, DOUT = 32, E = 80000;
constexpr int NT = (N + 63) / 64;  // 79 tiles

typedef unsigned short u16;
typedef __attribute__((ext_vector_type(8))) short short8;
typedef __attribute__((ext_vector_type(4))) float floatx4;

#define MFMA16(a, b, c) __builtin_amdgcn_mfma_f32_16x16x32_bf16((a), (b), (c), 0, 0, 0)

__device__ __forceinline__ u16 f2bf(float f) {
  union { float f; unsigned u; } v; v.f = f;
  unsigned r = v.u + 0x7FFFu + ((v.u >> 16) & 1u);  // RNE
  return (u16)(r >> 16);
}
__device__ __forceinline__ float bf2f(u16 s) {
  union { unsigned u; float f; } v; v.u = ((unsigned)s) << 16;
  return v.f;
}
__device__ __forceinline__ float sigmoid_fast(float x) {
  return __builtin_amdgcn_rcpf(1.f + __expf(-x));   // saturates cleanly at +-inf
}
__device__ __forceinline__ float tanh_fast(float x) {
  return fmaf(2.f, __builtin_amdgcn_rcpf(1.f + __expf(-2.f * x)), -1.f);
}

// ---------------- graph build ----------------

__global__ void count_kernel(const int* __restrict__ ei, int* counts) {
  int e = blockIdx.x * 256 + threadIdx.x;
  if (e < E) atomicAdd(&counts[ei[E + e]], 1);
}

// scan also re-zeroes counts (fill_kernel reuses counts as its cursor array)
__global__ void scan_kernel(int* counts, int* rowptr, float* dis) {
  __shared__ int sdata[1024];
  const int tid = threadIdx.x;
  constexpr int CH = (N + 1023) / 1024;  // 5
  int local[CH], cnt[CH];
  int s = 0;
  for (int i = 0; i < CH; i++) {
    int idx = tid * CH + i;
    int c = (idx < N) ? counts[idx] : 0;
    cnt[i] = c;
    local[i] = s;
    s += c;
  }
  sdata[tid] = s;
  __syncthreads();
  for (int off = 1; off < 1024; off <<= 1) {
    int v = (tid >= off) ? sdata[tid - off] : 0;
    __syncthreads();
    sdata[tid] += v;
    __syncthreads();
  }
  int prev = (tid > 0) ? sdata[tid - 1] : 0;
  for (int i = 0; i < CH; i++) {
    int idx = tid * CH + i;
    if (idx < N) {
      rowptr[idx] = prev + local[i];
      dis[idx] = rsqrtf((float)(cnt[i] + 1));  // + self loop
      counts[idx] = 0;                         // reset cursor for fill
    }
  }
  if (tid == 1023) rowptr[N] = sdata[1023];
}

__global__ void fill_kernel(const int* __restrict__ ei, const int* __restrict__ rowptr,
                            const float* __restrict__ dis, int* counts,
                            int* csr_src, float* csr_w) {
  int e = blockIdx.x * 256 + threadIdx.x;
  if (e >= E) return;
  int r = ei[e], c = ei[E + e];
  int pos = rowptr[c] + atomicAdd(&counts[c], 1);
  csr_src[pos] = r;
  csr_w[pos] = dis[r] * dis[c];
}

// ---------------- weight packing ----------------
// Algebraic fold: gate_pre = xs @ (Wg @ Wl_low) + H @ Wl_high + (bg @ Wl_low + bl)
// B-frag convention (16x16x32): lane l holds B[k=(l>>4)*8+jj][n=l&15], jj linear.
// wcB: combined conv weights [64x128] per gate, chunk c = g*16 + kt*8 + nt (kt<2)
// whB: Wl high-half [128x128] per gate, chunk c = g*32 + kt*8 + nt (kt<4)
// bcAll[g*128+n] = bg_g @ Wl_low + bl_g

__global__ void pack_kernel(const float* Wgz, const float* Wgr, const float* Wgh,
                            const float* Wlz, const float* Wlr, const float* Wlh,
                            const float* bgz, const float* bgr, const float* bgh,
                            const float* blz, const float* blr, const float* blh,
                            u16* wcB, u16* whB, float* bcAll) {
  int t = blockIdx.x * 256 + threadIdx.x;
  const float* Wg[3] = {Wgz, Wgr, Wgh};
  const float* Wl[3] = {Wlz, Wlr, Wlh};
  const float* bg[3] = {bgz, bgr, bgh};
  const float* bl[3] = {blz, blr, blh};
  if (t < 48 * 64) {
    // combined conv weights: Wc_g[k][n] = sum_j Wg_g[k][j] * Wl_g[j][n]
    int chunk = t >> 6, lane = t & 63;
    int q = lane >> 4, lm = lane & 15;
    int g = chunk >> 4, rem = chunk & 15, kt = rem >> 3, nt = rem & 7;
    int n = nt * 16 + lm;
#pragma unroll
    for (int jj = 0; jj < 8; jj++) {
      int k = kt * 32 + q * 8 + jj;   // < 64
      float acc = 0.f;
      for (int j = 0; j < DMID; j++)
        acc = fmaf(Wg[g][k * DMID + j], Wl[g][j * DMID + n], acc);
      wcB[(size_t)(chunk * 64 + lane) * 8 + jj] = f2bf(acc);
    }
  } else if (t < 48 * 64 + 96 * 64) {
    int t2 = t - 48 * 64;
    int chunk = t2 >> 6, lane = t2 & 63;
    int q = lane >> 4, lm = lane & 15;
    int g = chunk >> 5, rem = chunk & 31, kt = rem >> 3, nt = rem & 7;
    int n = nt * 16 + lm;
#pragma unroll
    for (int jj = 0; jj < 8; jj++) {
      int k = kt * 32 + q * 8 + jj;   // < 128
      whB[(size_t)t2 * 8 + jj] = f2bf(Wl[g][(DMID + k) * DMID + n]);
    }
  } else {
    int t3 = t - 48 * 64 - 96 * 64;
    if (t3 < 384) {
      int g = t3 >> 7, n = t3 & 127;
      float acc = bl[g][n];
      for (int j = 0; j < DMID; j++)
        acc = fmaf(bg[g][j], Wl[g][j * DMID + n], acc);
      bcAll[t3] = acc;
    }
  }
}

// ---------------- aggregation (v2): xs = S @ x, bf16 out ----------------
// 16 lanes per (b,n) unit, float4 per lane, 4 independent units per wave.
// Unroll-4 gather loop keeps 4 float4 gathers in flight per lane.
// Bijective XCD-chunked swizzle keeps each XCD's gathers within ~1 batch of x.
// (v3 one-block-per-node variant regressed ~85us: scattering each edge's reads
//  across 64 batch regions is L3-random; keep the per-batch L2-friendly walk.)

__global__ __launch_bounds__(256) void agg_kernel(
    const float* __restrict__ x, const int* __restrict__ rowptr,
    const int* __restrict__ csr_src, const float* __restrict__ csr_w,
    const float* __restrict__ dis, u16* __restrict__ xs) {
  constexpr int G = B * N / 16;  // 20000 blocks, G % 8 == 0
  const int bid = blockIdx.x;
  const int nb = (bid & 7) * (G >> 3) + (bid >> 3);  // XCD-chunked, bijective
  const int sub = threadIdx.x >> 4;      // 0..15
  const int l16 = threadIdx.x & 15;
  const int unit = nb * 16 + sub;        // b*N + n
  const int b = unit / N;
  const int n = unit - b * N;
  const float* xb = x + (size_t)b * N * DIN;
  const float d = dis[n];
  float4 v = *(const float4*)(xb + (size_t)n * DIN + l16 * 4);
  const float sw = d * d;
  float ax = v.x * sw, ay = v.y * sw, az = v.z * sw, aw = v.w * sw;
  const int s1 = rowptr[n + 1];
  int p = rowptr[n];
  for (; p + 4 <= s1; p += 4) {
    int i0 = csr_src[p], i1 = csr_src[p + 1], i2 = csr_src[p + 2], i3 = csr_src[p + 3];
    float w0 = csr_w[p], w1 = csr_w[p + 1], w2 = csr_w[p + 2], w3 = csr_w[p + 3];
    float4 a0 = *(const float4*)(xb + (size_t)i0 * DIN + l16 * 4);
    float4 a1 = *(const float4*)(xb + (size_t)i1 * DIN + l16 * 4);
    float4 a2 = *(const float4*)(xb + (size_t)i2 * DIN + l16 * 4);
    float4 a3 = *(const float4*)(xb + (size_t)i3 * DIN + l16 * 4);
    ax = fmaf(a0.x, w0, ax); ay = fmaf(a0.y, w0, ay);
    az = fmaf(a0.z, w0, az); aw = fmaf(a0.w, w0, aw);
    ax = fmaf(a1.x, w1, ax); ay = fmaf(a1.y, w1, ay);
    az = fmaf(a1.z, w1, az); aw = fmaf(a1.w, w1, aw);
    ax = fmaf(a2.x, w2, ax); ay = fmaf(a2.y, w2, ay);
    az = fmaf(a2.z, w2, az); aw = fmaf(a2.w, w2, aw);
    ax = fmaf(a3.x, w3, ax); ay = fmaf(a3.y, w3, ay);
    az = fmaf(a3.z, w3, az); aw = fmaf(a3.w, w3, aw);
  }
  for (; p < s1; p++) {
    int i0 = csr_src[p];
    float w0 = csr_w[p];
    float4 a0 = *(const float4*)(xb + (size_t)i0 * DIN + l16 * 4);
    ax = fmaf(a0.x, w0, ax); ay = fmaf(a0.y, w0, ay);
    az = fmaf(a0.z, w0, az); aw = fmaf(a0.w, w0, aw);
  }
  uint2 o;
  o.x = (unsigned)f2bf(ax) | ((unsigned)f2bf(ay) << 16);
  o.y = (unsigned)f2bf(az) | ((unsigned)f2bf(aw) << 16);
  *(uint2*)(xs + (size_t)unit * DIN + l16 * 4) = o;
}

// ---------------- fused MFMA kernel (barrier-free, wave-independent) ----------------
// 256 threads = 4 waves; wave w owns rows [w*16, w*16+16) and touches only its
// own 16 LDS rows. No __syncthreads.
// Two-phase, zpre-free register schedule (peak live ~95 regs, fits (256,4)'s
// 128-unified cap with NO scratch spill — WRITE_SIZE ~171MB is the witness):
//   ph1: r-gate + H*R in place per nt (H stashed as raw bf16 bits, uint2 x 8)
//   ph2: z & h gates together per nt (za,ha side-by-side; ah + ahr both live,
//        but zpre's 32 regs are gone) + blend + store
// LDS: 64*136*2 = 17408 B.

constexpr int SH = 136;  // stride for 128-wide bf16 tiles (16B-aligned rows)

__global__ __launch_bounds__(256, 4) void fused_mfma(
    const u16* __restrict__ xs, const float* __restrict__ H,
    const u16* __restrict__ wcB, const u16* __restrict__ whB,
    const float* __restrict__ bcAll,
    float* __restrict__ hnew, float* __restrict__ partials) {
  __shared__ u16 H_s[64 * SH];  // H tile bf16; each wave owns 16 rows

  const int tid = threadIdx.x;
  const int b = blockIdx.y;
  const int n0 = blockIdx.x * 64;
  const int lane = tid & 63, w = tid >> 6;
  const int q = lane >> 4, lm = lane & 15;
  const int w16 = w * 16;

  // ---- stage this wave's 16 H rows, fp32 -> bf16 ----
#pragma unroll
  for (int j = 0; j < 8; j++) {
    int idx = j * 64 + lane;            // 0..511
    int rl = idx >> 5, seg = idx & 31;  // row-local 0..15, col-seg 0..31
    int row = w16 + rl;
    float4 v = make_float4(0.f, 0.f, 0.f, 0.f);
    if (n0 + row < N) v = *(const float4*)(H + ((size_t)b * N + n0 + row) * DMID + seg * 4);
    uint2 p;
    p.x = (unsigned)f2bf(v.x) | ((unsigned)f2bf(v.y) << 16);
    p.y = (unsigned)f2bf(v.z) | ((unsigned)f2bf(v.w) << 16);
    *(uint2*)&H_s[row * SH + seg * 4] = p;
  }

  // ---- xs A-frags direct from global ----
  const int an = n0 + w16 + lm;  // this lane's A-row
  short8 ax[2];
  if (an < N) {
    const u16* xrow = xs + ((size_t)b * N + an) * DIN;
    ax[0] = *(const short8*)(xrow + q * 8);
    ax[1] = *(const short8*)(xrow + 32 + q * 8);
  } else {
    ax[0] = short8{0, 0, 0, 0, 0, 0, 0, 0};
    ax[1] = short8{0, 0, 0, 0, 0, 0, 0, 0};
  }

  // ---- H A-frags (own rows; ds-ordering via lgkmcnt, no barrier needed) ----
  short8 ah[4];
#pragma unroll
  for (int kt = 0; kt < 4; kt++)
    ah[kt] = *(const short8*)&H_s[(w16 + lm) * SH + kt * 32 + q * 8];

  // ---- phase 1: r gate fused with H*R in-place update (own rows) ----
  // hstash: raw bf16 bits of original H (C layout), 2 regs per nt.
  uint2 hstash[8];
#pragma unroll
  for (int nt = 0; nt < 8; nt++) {
    floatx4 a = {0.f, 0.f, 0.f, 0.f};
#pragma unroll
    for (int kt = 0; kt < 2; kt++)
      a = MFMA16(ax[kt], *(const short8*)(wcB + (size_t)((16 + kt * 8 + nt) * 64 + lane) * 8), a);
#pragma unroll
    for (int kt = 0; kt < 4; kt++)
      a = MFMA16(ah[kt], *(const short8*)(whB + (size_t)((32 + kt * 8 + nt) * 64 + lane) * 8), a);
    float bias = bcAll[128 + nt * 16 + lm];
    unsigned hx = 0u, hy = 0u;
#pragma unroll
    for (int r = 0; r < 4; r++) {
      int row = w16 + q * 4 + r, col = nt * 16 + lm;
      u16 hb = H_s[row * SH + col];
      float h = bf2f(hb);
      float rg = sigmoid_fast(a[r] + bias);
      H_s[row * SH + col] = f2bf(h * rg);
      if (r < 2) hx |= ((unsigned)hb) << (16 * r);
      else       hy |= ((unsigned)hb) << (16 * (r - 2));
    }
    hstash[nt] = make_uint2(hx, hy);
  }

  // ---- HR A-frags (own rows, written by this wave in phase 1) ----
  short8 ahr[4];
#pragma unroll
  for (int kt = 0; kt < 4; kt++)
    ahr[kt] = *(const short8*)&H_s[(w16 + lm) * SH + kt * 32 + q * 8];

  // ---- phase 2: z & h gates together per nt, blend, store, partial sums ----
#pragma unroll
  for (int nt = 0; nt < 8; nt++) {
    floatx4 za = {0.f, 0.f, 0.f, 0.f}, ha = {0.f, 0.f, 0.f, 0.f};
#pragma unroll
    for (int kt = 0; kt < 2; kt++) {
      za = MFMA16(ax[kt], *(const short8*)(wcB + (size_t)((0 + kt * 8 + nt) * 64 + lane) * 8), za);
      ha = MFMA16(ax[kt], *(const short8*)(wcB + (size_t)((32 + kt * 8 + nt) * 64 + lane) * 8), ha);
    }
#pragma unroll
    for (int kt = 0; kt < 4; kt++) {
      za = MFMA16(ah[kt], *(const short8*)(whB + (size_t)((0 + kt * 8 + nt) * 64 + lane) * 8), za);
      ha = MFMA16(ahr[kt], *(const short8*)(whB + (size_t)((64 + kt * 8 + nt) * 64 + lane) * 8), ha);
    }
    float zb = bcAll[nt * 16 + lm], hb_ = bcAll[256 + nt * 16 + lm];
    float colsum = 0.f;
#pragma unroll
    for (int r = 0; r < 4; r++) {
      int row = w16 + q * 4 + r;
      bool valid = (n0 + row) < N;
      unsigned word = (r < 2) ? hstash[nt].x : hstash[nt].y;
      float h = bf2f((u16)(word >> (16 * (r & 1))));
      float z = sigmoid_fast(za[r] + zb);
      float ht = tanh_fast(ha[r] + hb_);
      float hn = fmaf(z, h - ht, ht);  // z*H + (1-z)*ht
      if (valid) {
        hnew[((size_t)b * N + n0 + row) * DMID + nt * 16 + lm] = hn;
        colsum += hn;
      }
    }
    colsum += __shfl_xor(colsum, 16);
    colsum += __shfl_xor(colsum, 32);
    if (lane < 16)
      partials[(((size_t)b * NT + blockIdx.x) * 4 + w) * DMID + nt * 16 + lane] = colsum;
  }
}

// ---------------- output head: reduce per-wave partials, relu, Wout ----------------

__global__ void out_kernel(const float* __restrict__ partials, const float* __restrict__ Wout,
                           const float* __restrict__ bout, float* __restrict__ y) {
  const int b = blockIdx.x;
  const int c = threadIdx.x;  // 128
  __shared__ float m[DMID];
  float acc = 0.f;
  for (int t = 0; t < NT * 4; t++)
    acc += partials[((size_t)b * NT * 4 + t) * DMID + c];
  m[c] = fmaxf(acc * (1.f / (float)N), 0.f);
  __syncthreads();
  if (c < DOUT) {
    float a2 = bout[c];
    for (int jj = 0; jj < DMID; jj++)
      a2 = fmaf(m[jj], Wout[jj * DOUT + c], a2);
    y[b * DOUT + c] = a2;
  }
}

}  // namespace

extern "C" void kernel_launch(void* const* d_in, const int* in_sizes, int n_in,
                              void* d_out, int out_size, void* d_ws, size_t ws_size,
                              hipStream_t stream) {
  const float* x = (const float*)d_in[0];
  const int* ei = (const int*)d_in[1];
  const float* H = (const float*)d_in[2];
  const float* Wgz = (const float*)d_in[3];
  const float* bgz = (const float*)d_in[4];
  const float* Wgr = (const float*)d_in[5];
  const float* bgr = (const float*)d_in[6];
  const float* Wgh = (const float*)d_in[7];
  const float* bgh = (const float*)d_in[8];
  const float* Wlz = (const float*)d_in[9];
  const float* blz = (const float*)d_in[10];
  const float* Wlr = (const float*)d_in[11];
  const float* blr = (const float*)d_in[12];
  const float* Wlh = (const float*)d_in[13];
  const float* blh = (const float*)d_in[14];
  const float* Wout = (const float*)d_in[15];
  const float* bout = (const float*)d_in[16];

  float* y = (float*)d_out;                        // [B, DOUT]
  float* hnew = (float*)d_out + (size_t)B * DOUT;  // [B, N, DMID]

  char* p = (char*)d_ws;
  auto carve = [&](size_t bytes) {
    char* q = p;
    p += (bytes + 255) & ~size_t(255);
    return q;
  };
  int* counts = (int*)carve((size_t)N * 4);
  int* rowptr = (int*)carve((size_t)(N + 1) * 4);
  int* csr_src = (int*)carve((size_t)E * 4);
  float* csr_w = (float*)carve((size_t)E * 4);
  float* dis = (float*)carve((size_t)N * 4);
  u16* wcB = (u16*)carve((size_t)48 * 64 * 8 * 2);
  u16* whB = (u16*)carve((size_t)96 * 64 * 8 * 2);
  float* bcAll = (float*)carve((size_t)384 * 4);
  float* partials = (float*)carve((size_t)B * NT * 4 * DMID * 4);  // 10.4 MB
  u16* xs = (u16*)carve((size_t)B * N * DIN * 2);  // ~41 MB

  hipMemsetAsync(counts, 0, (size_t)N * 4, stream);
  pack_kernel<<<38, 256, 0, stream>>>(Wgz, Wgr, Wgh, Wlz, Wlr, Wlh,
                                      bgz, bgr, bgh, blz, blr, blh,
                                      wcB, whB, bcAll);
  count_kernel<<<(E + 255) / 256, 256, 0, stream>>>(ei, counts);
  scan_kernel<<<1, 1024, 0, stream>>>(counts, rowptr, dis);
  fill_kernel<<<(E + 255) / 256, 256, 0, stream>>>(ei, rowptr, dis, counts, csr_src, csr_w);
  agg_kernel<<<B * N / 16, 256, 0, stream>>>(x, rowptr, csr_src, csr_w, dis, xs);
  fused_mfma<<<dim3(NT, B), 256, 0, stream>>>(xs, H, wcB, whB, bcAll, hnew, partials);
  out_kernel<<<B, DMID, 0, stream>>>(partials, Wout, bout, y);
}